// Round 6
// baseline (1046.761 us; speedup 1.0000x reference)
//
#include <hip/hip_runtime.h>

// WaveNet (nsynth batch-folding) on MI355X — persistent kernel, v6.
// Stream identity: batch-folding dilation == dilated conv over one 8192-sample
// stream, j = l*2 + n; fold-d taps at j +- 2d, zero-pad at stream ends.
//
// v6: weights are pre-packed by prep into FRAGMENT-STREAM order: for each
// (layer, chunk c<32, wave w<8, quarter q<4) a contiguous 1KB lane-ordered
// block. The kernel streams them L2 -> VGPR through a statically-indexed
// 4-deep register ring (fully unrolled loops), eliminating the B LDS
// round-trip entirely (LDS keeps only the A broadcast + res exchange).
// Ring prefetch crosses phase boundaries and the grid barrier.
// H/S fp32 masters stay in registers (v5); bf16 Hb mirror is the only
// per-layer global activation traffic.

#define TS 8192
#define NL 30
#define NBLK 256
#define LSTRIDE 524288   // halfwords per layer in WF = 32*8*4*64*8

typedef __attribute__((ext_vector_type(8))) short bf16x8;
typedef __attribute__((ext_vector_type(4))) float f32x4;

__device__ __forceinline__ unsigned short f2bf(float f) {
    union { float f; unsigned int u; } v; v.f = f;
    unsigned int u = v.u;
    u += 0x7fffu + ((u >> 16) & 1u);   // RNE
    return (unsigned short)(u >> 16);
}

#define LGKM0() asm volatile("s_waitcnt lgkmcnt(0)" ::: "memory")
#define SBAR()  __builtin_amdgcn_s_barrier()
#define MFMA16(a, b, c) __builtin_amdgcn_mfma_f32_16x16x32_bf16((a), (b), (c), 0, 0, 0)

__device__ __forceinline__ int swz_jb(int bid) {   // XCD-chunked j-tile map
    return ((bid & 7) << 5) | (bid >> 3);
}

// ---------------------------------------------------------------------------
// Weight prep: fragment-stream layout.
// WF element (k, c, w, q, L, j):  offset = k*LSTRIDE + c*16384 + w*2048
//                                          + q*512 + L*8 + j   (halfwords)
// c<24: tap t=c>>3, kc=c&7; q<2 -> gate rows 32w+(q&1)*16+n; q>=2 -> feat.
// c>=24: kc=c-24; out col 64w+q*16+n (thru if <256 else skip).
// n = L&15 (N index), K col = kc*32 + (L>>4)*8 + j.
// ---------------------------------------------------------------------------
__global__ void prep_weights_kernel(
    const float* __restrict__ gw, const float* __restrict__ fw,
    const float* __restrict__ tw, const float* __restrict__ sw,
    const float* __restrict__ iw, const float* __restrict__ fnw,
    unsigned short* __restrict__ WF,
    unsigned short* __restrict__ Wib, unsigned short* __restrict__ Wfb)
{
    const int idx = blockIdx.x * blockDim.x + threadIdx.x;
    const int stride = gridDim.x * blockDim.x;
    const int total = NL * 65536;            // (k,c,w,q,L) tuples
    for (int i = idx; i < total; i += stride) {
        const int L = i & 63;
        const int q = (i >> 6) & 3;
        const int w = (i >> 8) & 7;
        const int c = (i >> 11) & 31;
        const int k = i >> 16;
        const int n  = L & 15;
        const int k8 = (L >> 4) * 8;
        unsigned short* dst = WF + (size_t)i * 8;
        if (c < 24) {
            const int t  = c >> 3;
            const int kc = c & 7;
            const int kbase = kc * 32 + k8;
            const int row = 32 * w + (q & 1) * 16 + n;
            const float* src = ((q < 2) ? gw : fw) + ((k * 256 + row) * 256 + kbase) * 3 + t;
            #pragma unroll
            for (int j = 0; j < 8; ++j) dst[j] = f2bf(src[j * 3]);
        } else {
            const int kc = c - 24;
            const int kbase = kc * 32 + k8;
            const int col = 64 * w + q * 16 + n;
            const float* src = ((col < 256) ? (tw + (k * 256 + col) * 256)
                                            : (sw + (k * 256 + col - 256) * 256)) + kbase;
            #pragma unroll
            for (int j = 0; j < 8; ++j) dst[j] = f2bf(src[j]);
        }
    }
    for (int i = idx; i < 256 * 256; i += stride) Wib[i] = f2bf(iw[i]);
    for (int i = idx; i < 256 * 256; i += stride) Wfb[i] = f2bf(fnw[i]);
}

// ---------------------------------------------------------------------------
// Grid barrier: monotonic counter, release/acquire at agent scope.
// ---------------------------------------------------------------------------
__device__ __forceinline__ void grid_barrier(unsigned* cnt, unsigned target, int tid) {
    __syncthreads();
    if (tid == 0) {
        __hip_atomic_fetch_add(cnt, 1u, __ATOMIC_RELEASE, __HIP_MEMORY_SCOPE_AGENT);
        while (__hip_atomic_load(cnt, __ATOMIC_RELAXED, __HIP_MEMORY_SCOPE_AGENT) < target)
            __builtin_amdgcn_s_sleep(2);
        (void)__hip_atomic_load(cnt, __ATOMIC_ACQUIRE, __HIP_MEMORY_SCOPE_AGENT);
    }
    __syncthreads();
}

// ---------------------------------------------------------------------------
__global__ __launch_bounds__(512, 2)
void wavenet_kernel(const float* __restrict__ x,
                    const float* __restrict__ init_w,
                    const float* __restrict__ init_b,
                    const unsigned short* __restrict__ Wib,
                    const float* __restrict__ ib,
                    const unsigned short* __restrict__ WF,
                    const float* __restrict__ gbA,
                    const float* __restrict__ fbA,
                    const unsigned short* __restrict__ Wfb,
                    const float* __restrict__ fbias,
                    unsigned short* __restrict__ Hb0,
                    unsigned short* __restrict__ Hb1,
                    float* __restrict__ out,
                    unsigned* __restrict__ counter)
{
    __shared__ __align__(16) unsigned short A_lds[3 * 32 * 256];   // 48 KB

    const int tid  = threadIdx.x;
    const int lane = tid & 63;
    const int w    = tid >> 6;
    const int j0   = swz_jb(blockIdx.x) * 32;
    const int arow = lane & 15;
    const int krow = lane >> 4;
    const int aswz = (arow & 7) << 4;
    const int cg0  = w * 32;
    const int c0   = w * 64;          // H cols (w<4) base
    const int cs0  = (w - 4) * 64;    // S cols (w>=4) base

    // persistent fp32 masters
    f32x4 state[2][4];
    // 4-deep B register ring (statically indexed everywhere)
    bf16x8 ring[4][4];

    // per-wave fragment-stream base (layer 0)
    const unsigned short* wb0 = WF + w * 2048 + lane * 8;

#define LOADC(BASE, C, S)                                                      \
    do {                                                                       \
        _Pragma("unroll")                                                      \
        for (int _q = 0; _q < 4; ++_q)                                         \
            ring[S][_q] = *(const bf16x8*)((BASE) + (C) * 16384 + _q * 512);   \
    } while (0)

    // ================= init conv -> state (waves 0-3), Hb0 + LDS tap1 ======
    if (w < 4) {
        #pragma unroll
        for (int rt = 0; rt < 2; ++rt)
            #pragma unroll
            for (int fc = 0; fc < 4; ++fc) {
                #pragma unroll
                for (int i = 0; i < 4; ++i) {
                    const int row = rt * 16 + krow * 4 + i;
                    const int col = c0 + fc * 16 + arow;
                    const int j   = j0 + row;
                    float acc = init_b[col];
                    #pragma unroll
                    for (int t = 0; t < 3; ++t) {
                        const int i2 = j + 2 * t - 2;
                        if (i2 >= 0 && i2 < TS)
                            acc += init_w[col * 3 + t] * x[(i2 & 1) * 4096 + (i2 >> 1)];
                    }
                    state[rt][fc][i] = acc;
                    const unsigned short hb = f2bf(acc);
                    Hb0[(j << 8) + col] = hb;
                    A_lds[((32 + row) << 8) + (((col << 1) ^ ((row & 7) << 4)) >> 1)] = hb;
                }
            }
    }
    LGKM0(); SBAR();   // H0 (bf16) visible in tap1

    // ================= iskip -> state (waves 4-7) ==========================
    if (w >= 4) {
        #pragma unroll
        for (int rt = 0; rt < 2; ++rt)
            #pragma unroll
            for (int fc = 0; fc < 4; ++fc) {
                const float b = ib[cs0 + fc * 16 + arow];
                state[rt][fc] = (f32x4){b, b, b, b};
            }
        #pragma unroll
        for (int kc = 0; kc < 8; ++kc) {
            const int aoff = ((kc * 64 + krow * 16) ^ aswz) >> 1;
            const bf16x8 a0 = *(const bf16x8*)(A_lds + ((32 + arow) << 8) + aoff);
            const bf16x8 a1 = *(const bf16x8*)(A_lds + ((48 + arow) << 8) + aoff);
            const int koff = kc * 32 + krow * 8;
            #pragma unroll
            for (int fc = 0; fc < 4; ++fc) {
                const bf16x8 bb = *(const bf16x8*)(Wib + ((cs0 + fc * 16 + arow) << 8) + koff);
                state[0][fc] = MFMA16(a0, bb, state[0][fc]);
                state[1][fc] = MFMA16(a1, bb, state[1][fc]);
            }
        }
    }

    // prefetch layer-0 chunks 0,1,2 (complete during the grid barrier)
    LOADC(wb0, 0, 0);
    LOADC(wb0, 1, 1);
    LOADC(wb0, 2, 2);

    unsigned target = NBLK;
    grid_barrier(counter, target, tid);

    const unsigned short* Hb_in = Hb0;
    unsigned short*       Hb_out = Hb1;

    // ============================ layer loop ================================
    for (int k = 0; k < NL; ++k) {
        const int d = 2 << (k % 10);   // stream dilation = 2 * 2^(k%10)
        const unsigned short* wbk = WF + (size_t)k * LSTRIDE + w * 2048 + lane * 8;
        const unsigned short* wbn = wbk + LSTRIDE;   // next layer (k<NL-1 only)
        const float gv0 = gbA[k * 256 + cg0 + arow];
        const float gv1 = gbA[k * 256 + cg0 + 16 + arow];
        const float fv0 = fbA[k * 256 + cg0 + arow];
        const float fv1 = fbA[k * 256 + cg0 + 16 + arow];

        // ---- A-stage: taps 0 and 2 only (center tap already in tap1) ----
        #pragma unroll
        for (int q = 0; q < 4; ++q) {
            const int cc  = tid + q * 512;
            const int c16 = cc & 31;
            const int m   = (cc >> 5) & 31;
            const int t   = (cc >> 10) << 1;            // 0 or 2
            const int r   = j0 + m + (t - 1) * d;
            uint4 v = make_uint4(0u, 0u, 0u, 0u);
            if (r >= 0 && r < TS)
                v = *(const uint4*)(Hb_in + (r << 8) + (c16 << 3));
            const int sb = (c16 << 4) ^ ((m & 7) << 4);
            *(uint4*)(A_lds + ((t * 32 + m) << 8) + (sb >> 1)) = v;
        }
        LGKM0(); SBAR();   // A complete

        // ---- phase 1: 24 chunks, register-ring prefetch depth 3 ----
        f32x4 accG[2][2], accF[2][2];
        accG[0][0] = (f32x4){gv0, gv0, gv0, gv0};
        accG[1][0] = accG[0][0];
        accG[0][1] = (f32x4){gv1, gv1, gv1, gv1};
        accG[1][1] = accG[0][1];
        accF[0][0] = (f32x4){fv0, fv0, fv0, fv0};
        accF[1][0] = accF[0][0];
        accF[0][1] = (f32x4){fv1, fv1, fv1, fv1};
        accF[1][1] = accF[0][1];

        #pragma unroll
        for (int c = 0; c < 24; ++c) {
            LOADC(wbk, c + 3, (c + 3) & 3);            // c+3 <= 26 < 32
            const int t = c >> 3, kc = c & 7;
            const int aoff = ((kc * 64 + krow * 16) ^ aswz) >> 1;
            const unsigned short* At = A_lds + ((t * 32 + arow) << 8);
            const bf16x8 a0 = *(const bf16x8*)(At + aoff);
            const bf16x8 a1 = *(const bf16x8*)(At + (16 << 8) + aoff);
            const int s = c & 3;
            accG[0][0] = MFMA16(a0, ring[s][0], accG[0][0]);
            accG[1][0] = MFMA16(a1, ring[s][0], accG[1][0]);
            accG[0][1] = MFMA16(a0, ring[s][1], accG[0][1]);
            accG[1][1] = MFMA16(a1, ring[s][1], accG[1][1]);
            accF[0][0] = MFMA16(a0, ring[s][2], accF[0][0]);
            accF[1][0] = MFMA16(a1, ring[s][2], accF[1][0]);
            accF[0][1] = MFMA16(a0, ring[s][3], accF[0][1]);
            accF[1][1] = MFMA16(a1, ring[s][3], accF[1][1]);
        }

        LGKM0(); SBAR();   // phase-1 LDS reads done (tap0 reused for res)

        // ---- res = sigmoid(G)*tanh(F) -> tap0 (swizzled) ----
        #pragma unroll
        for (int rt = 0; rt < 2; ++rt)
            #pragma unroll
            for (int fc = 0; fc < 2; ++fc)
                #pragma unroll
                for (int i = 0; i < 4; ++i) {
                    const float g = accG[rt][fc][i];
                    const float f = accF[rt][fc][i];
                    const float sg = 1.0f / (1.0f + __expf(-g));
                    const float e2 = __expf(2.0f * f);
                    const float th = 1.0f - 2.0f / (e2 + 1.0f);
                    const float rr = sg * th;
                    const int row = rt * 16 + krow * 4 + i;
                    const int col = cg0 + fc * 16 + arow;
                    A_lds[(row << 8) + (((col << 1) ^ ((row & 7) << 4)) >> 1)] = f2bf(rr);
                }
        LGKM0(); SBAR();   // res visible (chunks 24-26 still in flight in ring)

        // ---- phase 2: 8 chunks; acc starts from persistent state ----
        f32x4 acc2[2][4];
        #pragma unroll
        for (int rt = 0; rt < 2; ++rt)
            #pragma unroll
            for (int fc = 0; fc < 4; ++fc)
                acc2[rt][fc] = state[rt][fc];

        #pragma unroll
        for (int p = 0; p < 8; ++p) {
            const int m = 24 + p;
            if (m + 3 < 32) {
                LOADC(wbk, m + 3, (m + 3) & 3);
            } else if (k < NL - 1) {
                LOADC(wbn, m + 3 - 32, (m + 3) & 3);   // next layer chunks 0-2
            }
            const int aoff = ((p * 64 + krow * 16) ^ aswz) >> 1;
            const bf16x8 a0 = *(const bf16x8*)(A_lds + (arow << 8) + aoff);
            const bf16x8 a1 = *(const bf16x8*)(A_lds + ((16 + arow) << 8) + aoff);
            const int s = m & 3;
            acc2[0][0] = MFMA16(a0, ring[s][0], acc2[0][0]);
            acc2[1][0] = MFMA16(a1, ring[s][0], acc2[1][0]);
            acc2[0][1] = MFMA16(a0, ring[s][1], acc2[0][1]);
            acc2[1][1] = MFMA16(a1, ring[s][1], acc2[1][1]);
            acc2[0][2] = MFMA16(a0, ring[s][2], acc2[0][2]);
            acc2[1][2] = MFMA16(a1, ring[s][2], acc2[1][2]);
            acc2[0][3] = MFMA16(a0, ring[s][3], acc2[0][3]);
            acc2[1][3] = MFMA16(a1, ring[s][3], acc2[1][3]);
        }

        // ---- state update (registers only) ----
        #pragma unroll
        for (int rt = 0; rt < 2; ++rt)
            #pragma unroll
            for (int fc = 0; fc < 4; ++fc)
                state[rt][fc] = acc2[rt][fc];

        if (k < NL - 1) {
            // waves 0-3: publish bf16 H to global (halo) + LDS tap1 (center)
            if (w < 4) {
                #pragma unroll
                for (int rt = 0; rt < 2; ++rt)
                    #pragma unroll
                    for (int fc = 0; fc < 4; ++fc)
                        #pragma unroll
                        for (int i = 0; i < 4; ++i) {
                            const int row = rt * 16 + krow * 4 + i;
                            const int col = c0 + fc * 16 + arow;
                            const unsigned short hb = f2bf(state[rt][fc][i]);
                            Hb_out[((j0 + row) << 8) + col] = hb;
                            A_lds[((32 + row) << 8) + (((col << 1) ^ ((row & 7) << 4)) >> 1)] = hb;
                        }
            }
            target += NBLK;
            grid_barrier(counter, target, tid);   // also drains next-layer ring loads

            unsigned short* tmp = (unsigned short*)Hb_in;
            Hb_in = Hb_out; Hb_out = tmp;
        } else {
            // last layer: S (waves 4-7) -> tap0 bf16 for the final GEMM
            LGKM0(); SBAR();   // all phase-2 tap0 reads done
            if (w >= 4) {
                #pragma unroll
                for (int rt = 0; rt < 2; ++rt)
                    #pragma unroll
                    for (int fc = 0; fc < 4; ++fc)
                        #pragma unroll
                        for (int i = 0; i < 4; ++i) {
                            const int row = rt * 16 + krow * 4 + i;
                            const int col = cs0 + fc * 16 + arow;
                            A_lds[(row << 8) + (((col << 1) ^ ((row & 7) << 4)) >> 1)] =
                                f2bf(state[rt][fc][i]);
                        }
            }
            LGKM0(); SBAR();
        }
    }

    // ================= final: out = Wfb @ S^T + fbias =======================
    {
        const int m0 = w * 32;   // co slice
        f32x4 facc[2][2];
        #pragma unroll
        for (int rt = 0; rt < 2; ++rt)
            #pragma unroll
            for (int fc = 0; fc < 2; ++fc)
                facc[rt][fc] = (f32x4){0.f, 0.f, 0.f, 0.f};

        #pragma unroll
        for (int kc = 0; kc < 8; ++kc) {
            const int koff = kc * 32 + krow * 8;
            const bf16x8 a0 = *(const bf16x8*)(Wfb + ((m0 + arow) << 8) + koff);
            const bf16x8 a1 = *(const bf16x8*)(Wfb + ((m0 + 16 + arow) << 8) + koff);
            const int aoff = ((kc * 64 + krow * 16) ^ aswz) >> 1;
            const bf16x8 b0 = *(const bf16x8*)(A_lds + (arow << 8) + aoff);
            const bf16x8 b1 = *(const bf16x8*)(A_lds + ((16 + arow) << 8) + aoff);
            facc[0][0] = MFMA16(a0, b0, facc[0][0]);
            facc[1][0] = MFMA16(a1, b0, facc[1][0]);
            facc[0][1] = MFMA16(a0, b1, facc[0][1]);
            facc[1][1] = MFMA16(a1, b1, facc[1][1]);
        }

        #pragma unroll
        for (int rt = 0; rt < 2; ++rt)
            #pragma unroll
            for (int fc = 0; fc < 2; ++fc)
                #pragma unroll
                for (int i = 0; i < 4; ++i) {
                    const int co = m0 + rt * 16 + krow * 4 + i;
                    const int jj = j0 + fc * 16 + arow;
                    out[((jj & 1) << 20) + (co << 12) + (jj >> 1)] = facc[rt][fc][i] + fbias[co];
                }
    }
#undef LOADC
}

// ---------------------------------------------------------------------------
extern "C" void kernel_launch(void* const* d_in, const int* in_sizes, int n_in,
                              void* d_out, int out_size, void* d_ws, size_t ws_size,
                              hipStream_t stream)
{
    const float* x       = (const float*)d_in[0];
    const float* init_w  = (const float*)d_in[1];
    const float* init_b  = (const float*)d_in[2];
    const float* iskip_w = (const float*)d_in[3];
    const float* iskip_b = (const float*)d_in[4];
    const float* gate_w  = (const float*)d_in[5];
    const float* gate_b  = (const float*)d_in[6];
    const float* feat_w  = (const float*)d_in[7];
    const float* feat_b  = (const float*)d_in[8];
    const float* skip_w  = (const float*)d_in[9];
    const float* thru_w  = (const float*)d_in[10];
    const float* final_w = (const float*)d_in[11];
    const float* final_b = (const float*)d_in[12];

    char* ws = (char*)d_ws;
    size_t off = 0;
    auto alloc = [&](size_t bytes) {
        void* p = ws + off;
        off += (bytes + 255) & ~(size_t)255;
        return p;
    };
    unsigned short* WF  = (unsigned short*)alloc((size_t)NL * LSTRIDE * 2);
    unsigned short* Wib = (unsigned short*)alloc(256 * 256 * 2);
    unsigned short* Wfb = (unsigned short*)alloc(256 * 256 * 2);
    unsigned short* Hb0 = (unsigned short*)alloc((size_t)TS * 256 * 2);
    unsigned short* Hb1 = (unsigned short*)alloc((size_t)TS * 256 * 2);
    unsigned*       cnt = (unsigned*)alloc(256);

    hipMemsetAsync((void*)cnt, 0, 256, stream);
    prep_weights_kernel<<<2048, 256, 0, stream>>>(gate_w, feat_w, thru_w, skip_w,
                                                  iskip_w, final_w, WF, Wib, Wfb);
    wavenet_kernel<<<NBLK, 512, 0, stream>>>(
        x, init_w, init_b, Wib, iskip_b, WF, gate_b, feat_b,
        Wfb, final_b, Hb0, Hb1, (float*)d_out, cnt);
}